// Round 5
// baseline (221.442 us; speedup 1.0000x reference)
//
#include <hip/hip_runtime.h>
#include <math.h>

// Static graph dims
#define BATCH   16384
#define IN_DIM  512
#define NH      128
#define NO      256
#define L2E     1.4426950408889634f

#define THREADS 1024
#define BPB     64                       // batch rows per block
#define XS      514                      // X row stride (u16): 512 + 2 pad
#define HS      65                       // H row stride (f32): 64 + 1 pad
#define OBTS    260                      // OBT row stride (f32): 256 + 4 pad, 16B-aligned
// LDS layout (bytes):
//   X   [64][514] u16   @ 0          65792
//   H   [128][65] f32   @ 65792      33280   (X+H = 99072)
//   OBT [64][260] f32   @ 0          66560   (overlay of X/H after final barrier)
//   offsH[129], offsO[257] int @ 99072  1544
#define LDS_BYTES (99072 + 1544)

__device__ __forceinline__ float fast_rcp(float x) { return __builtin_amdgcn_rcpf(x); }
__device__ __forceinline__ float fast_exp2(float x) {
#if __has_builtin(__builtin_amdgcn_exp2f)
    return __builtin_amdgcn_exp2f(x);
#else
    return exp2f(x);
#endif
}
__device__ __forceinline__ int rfl(int v) { return __builtin_amdgcn_readfirstlane(v); }

// act ids: 1=identity, 2=tanh, 3=relu, 4=sigmoid. a,k wave-uniform (SGPR).
__device__ __forceinline__ float edge_act2(float z, int a, float k) {
    float ex = fast_exp2(k * z);
    float rc = fast_rcp(1.f + ex);
    return (a == 2) ? (1.f - 2.f * rc) : ((a == 4) ? rc : ((a == 3) ? fmaxf(z, 0.f) : z));
}
__device__ __forceinline__ float fast_tanh(float z) {
    float ex = fast_exp2(2.f * L2E * z);
    return 1.f - 2.f * fast_rcp(1.f + ex);
}
__device__ __forceinline__ float act_k(int a) {
    return (a == 2) ? (2.f * L2E) : ((a == 4) ? -L2E : 0.f);
}

__device__ __forceinline__ unsigned short f2bf_rne(float f) {
    unsigned int u = __float_as_uint(f);
    unsigned int r = (u + 0x7FFFu + ((u >> 16) & 1u)) >> 16;
    return (unsigned short)r;
}
__device__ __forceinline__ float bf2f(unsigned short h) {
    return __uint_as_float(((unsigned int)h) << 16);
}

__device__ __forceinline__ int lower_bound_dev(const int* __restrict__ arr, int n, int v) {
    int lo = 0, hi = n;
    while (lo < hi) { int m = (lo + hi) >> 1; if (arr[m] < v) lo = m + 1; else hi = m; }
    return lo;
}

// One fused kernel: block = 64-batch slice x whole network. lane = batch elem.
// X (bf16) + H (f32) live in LDS; edge records are wave-uniform scalar loads.
// No workspace, no atomics (edges are row-sorted; waves own disjoint rows).
__global__ __launch_bounds__(THREADS)
void wann_fused(const float* __restrict__ x,
                const int* __restrict__ rows_h, const int* __restrict__ cols_h,
                const int* __restrict__ acts_h, const float* __restrict__ wh,
                const int* __restrict__ rows_o, const int* __restrict__ cols_o,
                const int* __restrict__ acts_o, const float* __restrict__ wo,
                float* __restrict__ out, int Eh, int Eo)
{
    extern __shared__ char lds[];
    unsigned short* X   = (unsigned short*)lds;           // [BPB][XS]
    float*          H   = (float*)(lds + 65792);          // [NH][HS]
    float*          OBT = (float*)lds;                    // [BPB][OBTS] overlay
    int*            offsH = (int*)(lds + 99072);          // [NH+1]
    int*            offsO = offsH + (NH + 1);             // [NO+1]

    const int tid  = threadIdx.x;
    const int lane = tid & 63;
    const int wv   = tid >> 6;            // 0..15
    const int rb   = blockIdx.x * BPB;

    const int* wh_i = (const int*)wh;
    const int* wo_i = (const int*)wo;

    // ---- stage x slice -> bf16 LDS (coalesced float4 reads) ----
    {
        const float4* xv = (const float4*)(x + (size_t)rb * IN_DIM);
        #pragma unroll
        for (int kk = 0; kk < (BPB * IN_DIM / 4) / THREADS; ++kk) {  // 8 iters
            int v = tid + kk * THREADS;
            int r = v >> 7;               // /128 float4 per row
            int i = v & 127;
            float4 f = xv[v];
            unsigned int lo = (unsigned int)f2bf_rne(f.x) | ((unsigned int)f2bf_rne(f.y) << 16);
            unsigned int hi = (unsigned int)f2bf_rne(f.z) | ((unsigned int)f2bf_rne(f.w) << 16);
            unsigned int* dst = (unsigned int*)&X[r * XS + i * 4];   // 4B-aligned (XS even)
            dst[0] = lo;
            dst[1] = hi;
        }
    }
    // ---- CSR row offsets via per-thread binary search (one-time, overlapped) ----
    if (tid <= NH) offsH[tid] = lower_bound_dev(rows_h, Eh, tid);
    else if (tid <= NH + 1 + NO) offsO[tid - (NH + 1)] = lower_bound_dev(rows_o, Eo, tid - (NH + 1));
    __syncthreads();

    // ---- hidden: wave wv owns rows [wv*8, wv*8+8) ----
    for (int r = wv * (NH / 16); r < (wv + 1) * (NH / 16); ++r) {
        const int e0 = rfl(offsH[r]);
        const int e1 = rfl(offsH[r + 1]);
        float acc = 0.f;
        #pragma unroll 4
        for (int e = e0; e < e1; ++e) {
            int   col = rfl(cols_h[e]);
            int   a   = rfl(acts_h[e]);
            float w   = __int_as_float(rfl(wh_i[e]));
            float k   = act_k(a);
            float xv  = bf2f(X[lane * XS + col]);
            acc += edge_act2(xv * w, a, k);
        }
        H[r * HS + lane] = acc;
    }
    __syncthreads();

    // ---- output: wave wv owns rows [wv*16, wv*16+16), results -> regs ----
    float res[NO / 16];
    #pragma unroll
    for (int rr = 0; rr < NO / 16; ++rr) {
        const int r  = wv * (NO / 16) + rr;
        const int e0 = rfl(offsO[r]);
        const int e1 = rfl(offsO[r + 1]);
        float acc = 0.f;
        #pragma unroll 4
        for (int e = e0; e < e1; ++e) {
            int   col = rfl(cols_o[e]);
            int   a   = rfl(acts_o[e]);
            float w   = __int_as_float(rfl(wo_i[e]));
            float k   = act_k(a);
            float v   = (col < IN_DIM) ? bf2f(X[lane * XS + col])
                                       : H[(col - IN_DIM) * HS + lane];
            acc += edge_act2(v * w, a, k);
        }
        res[rr] = fast_tanh(acc);
    }
    __syncthreads();          // all X/H reads done -> safe to overlay with OBT

    // ---- epilogue: OBT[b][r] transpose buffer, then coalesced float4 stores ----
    #pragma unroll
    for (int rr = 0; rr < NO / 16; ++rr)
        OBT[lane * OBTS + wv * (NO / 16) + rr] = res[rr];
    __syncthreads();

    #pragma unroll
    for (int kk = 0; kk < (BPB * NO / 4) / THREADS; ++kk) {  // 4 iters
        int v  = tid + kk * THREADS;
        int c4 = v & 63;                  // float4 index within out row
        int b  = v >> 6;                  // batch row within block
        float4 o = *(const float4*)&OBT[b * OBTS + c4 * 4];  // b128, full bank BW
        *(float4*)&out[(size_t)(rb + b) * NO + c4 * 4] = o;
    }
}

extern "C" void kernel_launch(void* const* d_in, const int* in_sizes, int n_in,
                              void* d_out, int out_size, void* d_ws, size_t ws_size,
                              hipStream_t stream) {
    const float* x      = (const float*)d_in[0];
    const float* wh     = (const float*)d_in[1];
    const float* wo     = (const float*)d_in[2];
    const int*   rows_h = (const int*)d_in[3];
    const int*   cols_h = (const int*)d_in[4];
    const int*   acts_h = (const int*)d_in[5];
    const int*   rows_o = (const int*)d_in[6];
    const int*   cols_o = (const int*)d_in[7];
    const int*   acts_o = (const int*)d_in[8];
    float*       out    = (float*)d_out;

    const int Eh = in_sizes[1];
    const int Eo = in_sizes[2];

    // Single fused launch; dynamic LDS (98.3 KB > 64 KB static limit).
    wann_fused<<<BATCH / BPB, THREADS, LDS_BYTES, stream>>>(
        x, rows_h, cols_h, acts_h, wh, rows_o, cols_o, acts_o, wo, out, Eh, Eo);
}

// Round 6
// 140.877 us; speedup vs baseline: 1.5719x; 1.5719x over previous
//
#include <hip/hip_runtime.h>
#include <math.h>

// Static graph dims
#define BATCH   16384
#define IN_DIM  512
#define NH      128
#define NO      256
#define L2E     1.4426950408889634f

__device__ __forceinline__ float fast_rcp(float x) { return __builtin_amdgcn_rcpf(x); }
__device__ __forceinline__ float fast_exp2(float x) {
#if __has_builtin(__builtin_amdgcn_exp2f)
    return __builtin_amdgcn_exp2f(x);
#else
    return exp2f(x);
#endif
}
__device__ __forceinline__ int rfl(int v) { return __builtin_amdgcn_readfirstlane(v); }

__device__ __forceinline__ float fast_tanh(float z) {
    float ex = fast_exp2(2.f * L2E * z);
    return 1.f - 2.f * fast_rcp(1.f + ex);
}
__device__ __forceinline__ float fast_sig(float z) {
    float ex = fast_exp2(-L2E * z);
    return fast_rcp(1.f + ex);
}
__device__ __forceinline__ float act_k(int a) {
    return (a == 2) ? (2.f * L2E) : ((a == 4) ? -L2E : 0.f);
}

// act ids: 1=identity, 2=tanh, 3=relu, 4=sigmoid. `a` is wave-uniform (SGPR)
// -> scalar branches; identity/relu edges skip the quarter-rate exp2/rcp.
__device__ __forceinline__ void acc_edge4(float4& acc, float4 v, float w, int a) {
    float zx = v.x * w, zy = v.y * w, zz = v.z * w, zw = v.w * w;
    if (a == 2) {
        acc.x += fast_tanh(zx); acc.y += fast_tanh(zy);
        acc.z += fast_tanh(zz); acc.w += fast_tanh(zw);
    } else if (a == 4) {
        acc.x += fast_sig(zx); acc.y += fast_sig(zy);
        acc.z += fast_sig(zz); acc.w += fast_sig(zw);
    } else if (a == 3) {
        acc.x += fmaxf(zx, 0.f); acc.y += fmaxf(zy, 0.f);
        acc.z += fmaxf(zz, 0.f); acc.w += fmaxf(zw, 0.f);
    } else {
        acc.x += zx; acc.y += zy; acc.z += zz; acc.w += zw;
    }
}

__device__ __forceinline__ unsigned int f2bf_rne(float f) {
    unsigned int u = __float_as_uint(f);
    return (u + 0x7FFFu + ((u >> 16) & 1u)) >> 16;
}
__device__ __forceinline__ float bf_lo(unsigned int u) { return __uint_as_float(u << 16); }
__device__ __forceinline__ float bf_hi(unsigned int u) { return __uint_as_float(u & 0xFFFF0000u); }

__device__ __forceinline__ int lower_bound_dev(const int* __restrict__ arr, int n, int v) {
    int lo = 0, hi = n;
    while (lo < hi) { int m = (lo + hi) >> 1; if (arr[m] < v) lo = m + 1; else hi = m; }
    return lo;
}

// XCD swizzle: 1024-block grids; the 16 row-group blocks of one 256-batch slice
// land on one XCD (blockIdx % 8 -> XCD heuristic). Slice ws: 256KB xt + 128KB Ht,
// 8 slices/XCD ~= 3 MB < 4 MB L2.
__device__ __forceinline__ void decode_bid(int bid, int rows_per_group, int& rb, int& rg) {
    int xcd = bid & 7;
    int k   = bid >> 3;            // 0..127
    int slice = xcd * 8 + (k & 7); // 0..63
    rg = k >> 3;                   // 0..15
    rb = slice * 256;
    (void)rows_per_group;
}

// ---------------- fused prep: transpose x -> bf16 xt[IN][B] + CSR + packed edges ----------------
__global__ __launch_bounds__(256)
void prep_fused(const float* __restrict__ x, unsigned short* __restrict__ xt,
                const int* __restrict__ rows_h, const int* __restrict__ cols_h,
                const int* __restrict__ acts_h, const float* __restrict__ wh,
                const int* __restrict__ rows_o, const int* __restrict__ cols_o,
                const int* __restrict__ acts_o, const float* __restrict__ wo,
                int Eh, int Eo, int tile_blocks,
                int* __restrict__ offs_h, int* __restrict__ offs_o,
                int4* __restrict__ packed_h, int4* __restrict__ packed_o) {
    __shared__ float tile[64 * 65];
    if ((int)blockIdx.x < tile_blocks) {
        const int b0 = (blockIdx.x & (BATCH / 64 - 1)) * 64;   // 256 tiles along batch
        const int c0 = (blockIdx.x / (BATCH / 64)) * 64;       // 8 along cols
        // read: 64 rows x 16 float4; scalar LDS writes (stride 65, conflict-free)
        #pragma unroll
        for (int it = 0; it < 4; ++it) {
            int v = threadIdx.x + it * 256;
            int r = v >> 4, i = v & 15;
            const float4* row = (const float4*)(x + (size_t)(b0 + r) * IN_DIM + c0);
            float4 f = row[i];
            tile[r * 65 + i * 4 + 0] = f.x;
            tile[r * 65 + i * 4 + 1] = f.y;
            tile[r * 65 + i * 4 + 2] = f.z;
            tile[r * 65 + i * 4 + 3] = f.w;
        }
        __syncthreads();
        // write: per col, 32 bf16-pairs; lane-stride-130 LDS reads = 2-way (free)
        #pragma unroll
        for (int it = 0; it < 8; ++it) {
            int v = threadIdx.x + it * 256;
            int c = v >> 5, p = v & 31;
            int b = p * 2;
            unsigned int u = f2bf_rne(tile[b * 65 + c]) | (f2bf_rne(tile[(b + 1) * 65 + c]) << 16);
            *(unsigned int*)&xt[(size_t)(c0 + c) * BATCH + b0 + b] = u;
        }
        return;
    }
    int t = (blockIdx.x - tile_blocks) * 256 + threadIdx.x;
    if (t <= NH) offs_h[t] = lower_bound_dev(rows_h, Eh, t);
    else if (t <= NH + 1 + NO) offs_o[t - (NH + 1)] = lower_bound_dev(rows_o, Eo, t - (NH + 1));
    int u = t - (NH + 1 + NO + 1);
    if (u >= 0 && u < Eh) {
        int a = acts_h[u];
        packed_h[u] = make_int4(cols_h[u], a, __float_as_int(wh[u]), 0);
    }
    u -= Eh;
    if (u >= 0 && u < Eo) {
        int a = acts_o[u];
        packed_o[u] = make_int4(cols_o[u], a, __float_as_int(wo[u]), 0);
    }
}

// ---------------- hidden: wave = 1 row x 256-batch slice, bf16 gathers, regs only ----------------
// 1024 blocks x 512 thr -> 8192 waves = 8/SIMD.
__global__ __launch_bounds__(512)
void hidden_kernel(const unsigned short* __restrict__ xt, const int* __restrict__ offs_h,
                   const int4* __restrict__ packed_h, float* __restrict__ Ht) {
    const int lane = threadIdx.x & 63;
    const int wv   = threadIdx.x >> 6;
    int rb, rg;
    decode_bid(blockIdx.x, 8, rb, rg);
    const int bi = rb + lane * 4;
    const int r  = rg * 8 + wv;

    const int e0 = rfl(offs_h[r]);
    const int e1 = rfl(offs_h[r + 1]);
    float4 acc = make_float4(0.f, 0.f, 0.f, 0.f);
    #pragma unroll 4
    for (int e = e0; e < e1; ++e) {
        int4 p  = packed_h[e];                       // uniform addr -> s_load
        int col = rfl(p.x);
        int a   = rfl(p.y);
        float w = __int_as_float(rfl(p.z));
        uint2 u = *(const uint2*)(xt + (size_t)col * BATCH + bi);
        float4 v = make_float4(bf_lo(u.x), bf_hi(u.x), bf_lo(u.y), bf_hi(u.y));
        acc_edge4(acc, v, w, a);
    }
    *(float4*)&Ht[(size_t)r * BATCH + bi] = acc;
}

// ---------------- output: wave = 2 rows x 256-batch slice; OB transpose in LDS ----------------
// 1024 blocks x 512 thr -> 8/SIMD. OBS=260 -> conflict-free epilogue.
#define OBS 260
__global__ __launch_bounds__(512)
void output_kernel(const unsigned short* __restrict__ xt, const float* __restrict__ Ht,
                   const int* __restrict__ offs_o, const int4* __restrict__ packed_o,
                   float* __restrict__ out) {
    __shared__ float OB[16 * OBS];   // 16.6 KB
    const int lane = threadIdx.x & 63;
    const int wv   = threadIdx.x >> 6;
    int rb, rg;
    decode_bid(blockIdx.x, 16, rb, rg);
    const int r0 = rg * 16;
    const int bi = rb + lane * 4;

    #pragma unroll
    for (int rr = wv * 2; rr < wv * 2 + 2; ++rr) {
        const int r  = r0 + rr;
        const int e0 = rfl(offs_o[r]);
        const int e1 = rfl(offs_o[r + 1]);
        float4 acc = make_float4(0.f, 0.f, 0.f, 0.f);
        #pragma unroll 4
        for (int e = e0; e < e1; ++e) {
            int4 p  = packed_o[e];
            int col = rfl(p.x);
            int a   = rfl(p.y);
            float w = __int_as_float(rfl(p.z));
            float4 v;
            if (col < IN_DIM) {                       // wave-uniform branch
                uint2 u = *(const uint2*)(xt + (size_t)col * BATCH + bi);
                v = make_float4(bf_lo(u.x), bf_hi(u.x), bf_lo(u.y), bf_hi(u.y));
            } else {
                v = *(const float4*)&Ht[(size_t)(col - IN_DIM) * BATCH + bi];
            }
            acc_edge4(acc, v, w, a);
        }
        OB[rr * OBS + lane * 4 + 0] = fast_tanh(acc.x);
        OB[rr * OBS + lane * 4 + 1] = fast_tanh(acc.y);
        OB[rr * OBS + lane * 4 + 2] = fast_tanh(acc.z);
        OB[rr * OBS + lane * 4 + 3] = fast_tanh(acc.w);
    }
    __syncthreads();
    // out[rb+b][r0 + c4*4 ..], float4 stores; OB column reads are <=2-way (free)
    #pragma unroll
    for (int it = 0; it < (256 * 16 / 4) / 512; ++it) {
        int v  = threadIdx.x + it * 512;
        int c4 = v & 3;
        int b  = v >> 2;
        float4 o;
        o.x = OB[(c4 * 4 + 0) * OBS + b];
        o.y = OB[(c4 * 4 + 1) * OBS + b];
        o.z = OB[(c4 * 4 + 2) * OBS + b];
        o.w = OB[(c4 * 4 + 3) * OBS + b];
        *(float4*)&out[(size_t)(rb + b) * NO + r0 + c4 * 4] = o;
    }
}

// ---------------- fallback: round-5 single fused kernel (no workspace needed) ----------------
#define FT      1024
#define FBPB    64
#define FXS     514
#define FHS     65
#define FOBTS   260
#define FLDS    (99072 + 1544)
__device__ __forceinline__ unsigned short f2bf16s(float f) { return (unsigned short)f2bf_rne(f); }
__device__ __forceinline__ float bf2f(unsigned short h) { return __uint_as_float(((unsigned int)h) << 16); }
__device__ __forceinline__ float edge_act2(float z, int a, float k) {
    float ex = fast_exp2(k * z);
    float rc = fast_rcp(1.f + ex);
    return (a == 2) ? (1.f - 2.f * rc) : ((a == 4) ? rc : ((a == 3) ? fmaxf(z, 0.f) : z));
}
__global__ __launch_bounds__(FT)
void wann_fused(const float* __restrict__ x,
                const int* __restrict__ rows_h, const int* __restrict__ cols_h,
                const int* __restrict__ acts_h, const float* __restrict__ wh,
                const int* __restrict__ rows_o, const int* __restrict__ cols_o,
                const int* __restrict__ acts_o, const float* __restrict__ wo,
                float* __restrict__ out, int Eh, int Eo)
{
    extern __shared__ char lds[];
    unsigned short* X   = (unsigned short*)lds;
    float*          H   = (float*)(lds + 65792);
    float*          OBT = (float*)lds;
    int*            offsH = (int*)(lds + 99072);
    int*            offsO = offsH + (NH + 1);
    const int tid  = threadIdx.x;
    const int lane = tid & 63;
    const int wv   = tid >> 6;
    const int rb   = blockIdx.x * FBPB;
    const int* wh_i = (const int*)wh;
    const int* wo_i = (const int*)wo;
    {
        const float4* xv = (const float4*)(x + (size_t)rb * IN_DIM);
        #pragma unroll
        for (int kk = 0; kk < (FBPB * IN_DIM / 4) / FT; ++kk) {
            int v = tid + kk * FT;
            int r = v >> 7, i = v & 127;
            float4 f = xv[v];
            unsigned int lo = (unsigned int)f2bf16s(f.x) | ((unsigned int)f2bf16s(f.y) << 16);
            unsigned int hi = (unsigned int)f2bf16s(f.z) | ((unsigned int)f2bf16s(f.w) << 16);
            unsigned int* dst = (unsigned int*)&X[r * FXS + i * 4];
            dst[0] = lo; dst[1] = hi;
        }
    }
    if (tid <= NH) offsH[tid] = lower_bound_dev(rows_h, Eh, tid);
    else if (tid <= NH + 1 + NO) offsO[tid - (NH + 1)] = lower_bound_dev(rows_o, Eo, tid - (NH + 1));
    __syncthreads();
    for (int r = wv * (NH / 16); r < (wv + 1) * (NH / 16); ++r) {
        const int e0 = rfl(offsH[r]); const int e1 = rfl(offsH[r + 1]);
        float acc = 0.f;
        #pragma unroll 4
        for (int e = e0; e < e1; ++e) {
            int col = rfl(cols_h[e]); int a = rfl(acts_h[e]);
            float w = __int_as_float(rfl(wh_i[e]));
            acc += edge_act2(bf2f(X[lane * FXS + col]) * w, a, act_k(a));
        }
        H[r * FHS + lane] = acc;
    }
    __syncthreads();
    float res[NO / 16];
    #pragma unroll
    for (int rr = 0; rr < NO / 16; ++rr) {
        const int r = wv * (NO / 16) + rr;
        const int e0 = rfl(offsO[r]); const int e1 = rfl(offsO[r + 1]);
        float acc = 0.f;
        #pragma unroll 4
        for (int e = e0; e < e1; ++e) {
            int col = rfl(cols_o[e]); int a = rfl(acts_o[e]);
            float w = __int_as_float(rfl(wo_i[e]));
            float v = (col < IN_DIM) ? bf2f(X[lane * FXS + col]) : H[(col - IN_DIM) * FHS + lane];
            acc += edge_act2(v * w, a, act_k(a));
        }
        res[rr] = fast_tanh(acc);
    }
    __syncthreads();
    #pragma unroll
    for (int rr = 0; rr < NO / 16; ++rr)
        OBT[lane * FOBTS + wv * (NO / 16) + rr] = res[rr];
    __syncthreads();
    #pragma unroll
    for (int kk = 0; kk < (FBPB * NO / 4) / FT; ++kk) {
        int v = tid + kk * FT;
        int c4 = v & 63, b = v >> 6;
        float4 o = *(const float4*)&OBT[b * FOBTS + c4 * 4];
        *(float4*)&out[(size_t)(rb + b) * NO + c4 * 4] = o;
    }
}

extern "C" void kernel_launch(void* const* d_in, const int* in_sizes, int n_in,
                              void* d_out, int out_size, void* d_ws, size_t ws_size,
                              hipStream_t stream) {
    const float* x      = (const float*)d_in[0];
    const float* wh     = (const float*)d_in[1];
    const float* wo     = (const float*)d_in[2];
    const int*   rows_h = (const int*)d_in[3];
    const int*   cols_h = (const int*)d_in[4];
    const int*   acts_h = (const int*)d_in[5];
    const int*   rows_o = (const int*)d_in[6];
    const int*   cols_o = (const int*)d_in[7];
    const int*   acts_o = (const int*)d_in[8];
    float*       out    = (float*)d_out;

    const int Eh = in_sizes[1];
    const int Eo = in_sizes[2];

    // ws layout: [offs_h@0][offs_o@1024][packed_h@4096][packed_o][xt bf16][Ht f32]
    char* ws = (char*)d_ws;
    int*  offs_h   = (int*)ws;
    int*  offs_o   = (int*)(ws + 1024);
    int4* packed_h = (int4*)(ws + 4096);
    int4* packed_o = packed_h + Eh;
    size_t tier_packed = 4096 + (size_t)(Eh + Eo) * 16;
    size_t xt_off      = (tier_packed + 255) & ~(size_t)255;
    unsigned short* xt = (unsigned short*)(ws + xt_off);
    size_t ht_off      = (xt_off + (size_t)IN_DIM * BATCH * 2 + 255) & ~(size_t)255;
    float* Ht          = (float*)(ws + ht_off);
    size_t need_full   = ht_off + (size_t)NH * BATCH * 4;

    const int ntasks      = (NH + 1) + (NO + 1) + Eh + Eo;
    const int edge_blocks = (ntasks + 255) / 256;
    const int tile_blocks = (BATCH / 64) * (IN_DIM / 64);   // 2048

    if (ws_size >= need_full) {
        prep_fused<<<tile_blocks + edge_blocks, 256, 0, stream>>>(
            x, xt, rows_h, cols_h, acts_h, wh, rows_o, cols_o, acts_o, wo,
            Eh, Eo, tile_blocks, offs_h, offs_o, packed_h, packed_o);
        hidden_kernel<<<1024, 512, 0, stream>>>(xt, offs_h, packed_h, Ht);
        output_kernel<<<1024, 512, 0, stream>>>(xt, Ht, offs_o, packed_o, out);
    } else {
        wann_fused<<<BATCH / FBPB, FT, FLDS, stream>>>(
            x, rows_h, cols_h, acts_h, wh, rows_o, cols_o, acts_o, wo, out, Eh, Eo);
    }
}